// Round 8
// baseline (205.712 us; speedup 1.0000x reference)
//
#include <hip/hip_runtime.h>
#include <hip/hip_bf16.h>

// B=2, T=2048, C=1024, H=16, D=64
// convx(X) -> convt(W_attn) -> qkv_gemm (256x192 8-wave counted-vmcnt) ->
// attn_v7 (2-way KV-split + merge) -> convt(W_proj) -> proj_gemm

typedef __attribute__((ext_vector_type(8))) short bf16x8;
typedef __attribute__((ext_vector_type(4))) short bf16x4;
typedef __attribute__((ext_vector_type(4))) float f32x4;

__device__ __forceinline__ short f2bs(float f) {
    union { __hip_bfloat16 h; short s; } u;
    u.h = __float2bfloat16(f);
    return u.s;
}

#define GLOAD_LDS16(gp, lp)                                                        \
    __builtin_amdgcn_global_load_lds((const __attribute__((address_space(1))) void*)(gp), \
                                     (__attribute__((address_space(3))) void*)(lp), 16, 0, 0)

// ---------------------------------------------------------------------------
// convx: X f32 [4096*1024] -> bf16.
// ---------------------------------------------------------------------------
__global__ __launch_bounds__(256) void convx(
    const float* __restrict__ X, short* __restrict__ Xb)
{
    const size_t i = ((size_t)blockIdx.x * 256 + threadIdx.x) * 8;
    float4 a = *(const float4*)(X + i);
    float4 b = *(const float4*)(X + i + 4);
    bf16x8 s;
    s[0] = f2bs(a.x); s[1] = f2bs(a.y); s[2] = f2bs(a.z); s[3] = f2bs(a.w);
    s[4] = f2bs(b.x); s[5] = f2bs(b.y); s[6] = f2bs(b.z); s[7] = f2bs(b.w);
    *(bf16x8*)(Xb + i) = s;
}

// ---------------------------------------------------------------------------
// convert + transpose: W f32 [K][N] -> Wt bf16 [N][K].
// ---------------------------------------------------------------------------
__global__ __launch_bounds__(256) void convt(
    const float* __restrict__ W, short* __restrict__ Wt, int K, int N)
{
    __shared__ short t[64 * 72];
    const int tid = threadIdx.x;
    const int n0 = blockIdx.x * 64, k0 = blockIdx.y * 64;
    #pragma unroll
    for (int i = 0; i < 4; i++) {
        int k = (tid >> 4) + i * 16;
        int n = (tid & 15) * 4;
        float4 v = *(const float4*)(W + (size_t)(k0 + k) * N + n0 + n);
        t[(n + 0) * 72 + k] = f2bs(v.x);
        t[(n + 1) * 72 + k] = f2bs(v.y);
        t[(n + 2) * 72 + k] = f2bs(v.z);
        t[(n + 3) * 72 + k] = f2bs(v.w);
    }
    __syncthreads();
    #pragma unroll
    for (int i = 0; i < 2; i++) {
        int n  = (tid >> 3) + i * 32;
        int kc = (tid & 7) * 8;
        bf16x8 v = *(const bf16x8*)&t[n * 72 + kc];
        *(bf16x8*)(Wt + (size_t)(n0 + n) * K + k0 + kc) = v;
    }
}

// ---------------------------------------------------------------------------
// Kernel 1: QKV GEMM, 256x192 tile, BK=64, 8 waves, double-buffered LDS with
// counted vmcnt, swizzled reads, setprio.
// ---------------------------------------------------------------------------
__global__ __launch_bounds__(512) void qkv_gemm(
    const short* __restrict__ Xb, const short* __restrict__ Wt,
    const float* __restrict__ bias,
    short* __restrict__ Qw, short* __restrict__ Kw, short* __restrict__ Vt)
{
    __shared__ short Alds[2][256 * 64];
    __shared__ short Blds[2][192 * 64];
    const int tid  = threadIdx.x;
    const int lane = tid & 63;
    const int wid  = tid >> 6;
    const int wm = wid >> 2, wn = wid & 3;
    const int g = lane >> 4, cc = lane & 15;
    const int sw = cc & 7;

    const int bid  = blockIdx.x;
    const int wgid = (bid & 7) * 32 + (bid >> 3);
    const int n0 = (wgid >> 4) * 192;
    const int m0 = (wgid & 15) * 256;

    f32x4 acc[8][3];
    const f32x4 z4 = {0.f, 0.f, 0.f, 0.f};
    #pragma unroll
    for (int i = 0; i < 8; i++)
        #pragma unroll
        for (int j = 0; j < 3; j++) acc[i][j] = z4;

    auto STAGE = [&](int t, int buf) {
        const int k0 = t * 64;
        #pragma unroll
        for (int j = 0; j < 4; j++) {
            int c = j * 512 + wid * 64 + lane;
            int row = c >> 3, sch = (c & 7) ^ (row & 7);
            GLOAD_LDS16(Xb + (size_t)(m0 + row) * 1024 + k0 + sch * 8,
                        &Alds[buf][c * 8]);
        }
        #pragma unroll
        for (int j = 0; j < 3; j++) {
            int c = j * 512 + wid * 64 + lane;
            int row = c >> 3, sch = (c & 7) ^ (row & 7);
            GLOAD_LDS16(Wt + (size_t)(n0 + row) * 1024 + k0 + sch * 8,
                        &Blds[buf][c * 8]);
        }
    };

    STAGE(0, 0);
    STAGE(1, 1);
    asm volatile("s_waitcnt vmcnt(7)" ::: "memory");
    asm volatile("s_barrier" ::: "memory");

    const int NT = 16;
    for (int t = 0; t < NT; t++) {
        const short* Ab = Alds[t & 1];
        const short* Bb = Blds[t & 1];

        bf16x8 bfr[3][2];
        #pragma unroll
        for (int nf = 0; nf < 3; nf++)
            #pragma unroll
            for (int kk = 0; kk < 2; kk++)
                bfr[nf][kk] = *(const bf16x8*)&Bb[(wn * 48 + nf * 16 + cc) * 64 +
                                                  ((kk * 4 + g) ^ sw) * 8];
        {
            bf16x8 af[4][2];
            #pragma unroll
            for (int mf = 0; mf < 4; mf++)
                #pragma unroll
                for (int kk = 0; kk < 2; kk++)
                    af[mf][kk] = *(const bf16x8*)&Ab[(wm * 128 + mf * 16 + cc) * 64 +
                                                     ((kk * 4 + g) ^ sw) * 8];
            __builtin_amdgcn_s_setprio(1);
            #pragma unroll
            for (int mf = 0; mf < 4; mf++)
                #pragma unroll
                for (int nf = 0; nf < 3; nf++)
                    #pragma unroll
                    for (int kk = 0; kk < 2; kk++)
                        acc[mf][nf] = __builtin_amdgcn_mfma_f32_16x16x32_bf16(
                            af[mf][kk], bfr[nf][kk], acc[mf][nf], 0, 0, 0);
            __builtin_amdgcn_s_setprio(0);
        }
        {
            bf16x8 af[4][2];
            #pragma unroll
            for (int mf = 0; mf < 4; mf++)
                #pragma unroll
                for (int kk = 0; kk < 2; kk++)
                    af[mf][kk] = *(const bf16x8*)&Ab[(wm * 128 + (mf + 4) * 16 + cc) * 64 +
                                                     ((kk * 4 + g) ^ sw) * 8];
            __builtin_amdgcn_s_setprio(1);
            #pragma unroll
            for (int mf = 0; mf < 4; mf++)
                #pragma unroll
                for (int nf = 0; nf < 3; nf++)
                    #pragma unroll
                    for (int kk = 0; kk < 2; kk++)
                        acc[mf + 4][nf] = __builtin_amdgcn_mfma_f32_16x16x32_bf16(
                            af[mf][kk], bfr[nf][kk], acc[mf + 4][nf], 0, 0, 0);
            __builtin_amdgcn_s_setprio(0);
        }

        asm volatile("s_barrier" ::: "memory");
        if (t + 2 < NT) {
            STAGE(t + 2, t & 1);
            asm volatile("s_waitcnt vmcnt(7)" ::: "memory");
            asm volatile("s_barrier" ::: "memory");
        } else if (t + 1 < NT) {
            asm volatile("s_waitcnt vmcnt(0)" ::: "memory");
            asm volatile("s_barrier" ::: "memory");
        }
    }

    const float QSCALE = 0.04508422976f;
    #pragma unroll
    for (int nf = 0; nf < 3; nf++) {
        int col = n0 + wn * 48 + nf * 16 + cc;
        int which = col >> 10;
        int ci = col & 1023;
        int h = ci >> 6, d = ci & 63;
        float bv = bias[col];
        #pragma unroll
        for (int mf = 0; mf < 8; mf++) {
            #pragma unroll
            for (int r = 0; r < 4; r++) {
                int row = m0 + wm * 128 + mf * 16 + g * 4 + r;
                int b = row >> 11, tt = row & 2047;
                int bh = b * 16 + h;
                float v = acc[mf][nf][r] + bv;
                if (which == 0)      Qw[((size_t)bh * 2048 + tt) * 64 + d] = f2bs(v * QSCALE);
                else if (which == 1) Kw[((size_t)bh * 2048 + tt) * 64 + d] = f2bs(v);
                else {
                    int tp = (tt & ~31) | (((tt >> 2) & 3) * 8 + ((tt >> 4) & 1) * 4 + (tt & 3));
                    Vt[((size_t)bh * 64 + d) * 2048 + tp] = f2bs(v);
                }
            }
        }
    }
}

// ---------------------------------------------------------------------------
// Kernel 2: causal flash attention v7. 128-thr block = 2 waves on ONE 32-row
// q-tile; wave s handles KV-steps st ≡ s (mod 2) with its own online-softmax
// state; LDS exchange + merge at the end. No LDS in the step loop.
// ---------------------------------------------------------------------------
#define ATTN_STEP(KF, VF, KN, VN, KVN, PRE, MSK, KV0)                             \
  {                                                                               \
    if (PRE) {                                                                    \
      _Pragma("unroll") for (int kvc = 0; kvc < 2; kvc++)                         \
      _Pragma("unroll") for (int ds = 0; ds < 2; ds++)                            \
        KN[kvc * 2 + ds] = *(const bf16x8*)(Kb + ((KVN) + kvc * 16 + cc) * 64 + ds * 32 + g * 8); \
      _Pragma("unroll") for (int ch = 0; ch < 4; ch++)                            \
        VN[ch] = *(const bf16x8*)(Vb + (ch * 16 + cc) * 2048 + (KVN) + g * 8);     \
    }                                                                             \
    f32x4 s_[2][2];                                                               \
    _Pragma("unroll") for (int qf = 0; qf < 2; qf++)                              \
    _Pragma("unroll") for (int kvc = 0; kvc < 2; kvc++) {                         \
      s_[qf][kvc] = z4;                                                           \
      _Pragma("unroll") for (int ds = 0; ds < 2; ds++)                            \
        s_[qf][kvc] = __builtin_amdgcn_mfma_f32_16x16x32_bf16(                    \
            KF[kvc * 2 + ds], qfr[qf][ds], s_[qf][kvc], 0, 0, 0);                 \
    }                                                                             \
    bf16x8 pb_[2];                                                                \
    _Pragma("unroll") for (int qf = 0; qf < 2; qf++) {                            \
      float sv[8];                                                                \
      _Pragma("unroll") for (int kvc = 0; kvc < 2; kvc++)                         \
      _Pragma("unroll") for (int r = 0; r < 4; r++) {                             \
        float v = s_[qf][kvc][r];                                                 \
        if (MSK) {                                                                \
          int kv = (KV0) + kvc * 16 + g * 4 + r;                                  \
          v = (kv <= q0 + qf * 16 + cc) ? v : -1e30f;                             \
        }                                                                         \
        sv[kvc * 4 + r] = v;                                                      \
      }                                                                           \
      float lm = fmaxf(fmaxf(fmaxf(sv[0], sv[1]), fmaxf(sv[2], sv[3])),           \
                       fmaxf(fmaxf(sv[4], sv[5]), fmaxf(sv[6], sv[7])));          \
      if (__any(lm > m_r[qf] + 6.0f)) {                                           \
        float mx = lm;                                                            \
        mx = fmaxf(mx, __shfl_xor(mx, 16));                                       \
        mx = fmaxf(mx, __shfl_xor(mx, 32));                                       \
        float mn = fmaxf(m_r[qf], mx);                                            \
        float a = exp2f(m_r[qf] - mn);                                            \
        _Pragma("unroll") for (int ch = 0; ch < 4; ch++)                          \
        _Pragma("unroll") for (int r = 0; r < 4; r++) o[qf][ch][r] *= a;          \
        l_l[qf] *= a;                                                             \
        m_r[qf] = mn;                                                             \
      }                                                                           \
      float rs = 0.f;                                                             \
      _Pragma("unroll") for (int i = 0; i < 8; i++) {                             \
        float p = exp2f(sv[i] - m_r[qf]);                                         \
        pb_[qf][i] = f2bs(p);                                                     \
        rs += p;                                                                  \
      }                                                                           \
      l_l[qf] += rs;                                                              \
    }                                                                             \
    _Pragma("unroll") for (int ch = 0; ch < 4; ch++) {                            \
      o[0][ch] = __builtin_amdgcn_mfma_f32_16x16x32_bf16(VF[ch], pb_[0], o[0][ch], 0, 0, 0); \
      o[1][ch] = __builtin_amdgcn_mfma_f32_16x16x32_bf16(VF[ch], pb_[1], o[1][ch], 0, 0, 0); \
    }                                                                             \
  }

__global__ __launch_bounds__(128, 4) void attn_v7(
    const short* __restrict__ Qw, const short* __restrict__ Kw,
    const short* __restrict__ Vt, short* __restrict__ Aout)
{
    __shared__ float Mrg[64 * 36];        // wave1's state: m[2], l[2], o[32]
    const int tid  = threadIdx.x;
    const int lane = tid & 63;
    const int ws   = tid >> 6;            // KV-split index 0/1
    const int g = lane >> 4, cc = lane & 15;
    const int bid = blockIdx.x;
    const int qt = 63 - (bid >> 5);       // longest tiles first
    const int bh = bid & 31;              // XCD = bh % 8
    const int q0 = qt * 32;
    const int b = bh >> 4, h = bh & 15;
    const short* Qb = Qw + (size_t)bh * 2048 * 64;
    const short* Kb = Kw + (size_t)bh * 2048 * 64;
    const short* Vb = Vt + (size_t)bh * 64 * 2048;

    bf16x8 qfr[2][2];
    #pragma unroll
    for (int qf = 0; qf < 2; qf++)
        #pragma unroll
        for (int ds = 0; ds < 2; ds++)
            qfr[qf][ds] = *(const bf16x8*)(Qb + (q0 + qf * 16 + cc) * 64 + ds * 32 + g * 8);

    const f32x4 z4 = {0.f, 0.f, 0.f, 0.f};
    f32x4 o[2][4];
    #pragma unroll
    for (int qf = 0; qf < 2; qf++)
        #pragma unroll
        for (int ch = 0; ch < 4; ch++) o[qf][ch] = z4;
    float m_r[2] = {-1e30f, -1e30f};
    float l_l[2] = {0.f, 0.f};

    // last step index of this wave: qt if qt%2==ws else qt-1
    const int lastSt = qt - ((qt ^ ws) & 1);
    const bool active = (lastSt >= ws);

    if (active) {
        bf16x8 kA[4], vA[4], kB[4], vB[4];
        const int kvS = ws * 32;
        #pragma unroll
        for (int kvc = 0; kvc < 2; kvc++)
            #pragma unroll
            for (int ds = 0; ds < 2; ds++)
                kA[kvc * 2 + ds] = *(const bf16x8*)(Kb + (kvS + kvc * 16 + cc) * 64 + ds * 32 + g * 8);
        #pragma unroll
        for (int ch = 0; ch < 4; ch++)
            vA[ch] = *(const bf16x8*)(Vb + (ch * 16 + cc) * 2048 + kvS + g * 8);

        int st = ws;
        const int mk = (lastSt == qt);
        while (st + 4 <= lastSt) {
            ATTN_STEP(kA, vA, kB, vB, (st + 2) * 32, 1, 0, 0);
            ATTN_STEP(kB, vB, kA, vA, (st + 4) * 32, 1, 0, 0);
            st += 4;
        }
        if (st + 2 <= lastSt) {
            ATTN_STEP(kA, vA, kB, vB, (st + 2) * 32, 1, 0, 0);
            ATTN_STEP(kB, vB, kB, vB, 0, 0, mk, lastSt * 32);
        } else {
            ATTN_STEP(kA, vA, kA, vA, 0, 0, mk, lastSt * 32);
        }
    }

    // per-wave l reduction across g-groups
    #pragma unroll
    for (int qf = 0; qf < 2; qf++) {
        float lt = l_l[qf];
        lt += __shfl_xor(lt, 16);
        lt += __shfl_xor(lt, 32);
        l_l[qf] = lt;
    }

    // merge the two KV-split halves
    if (ws == 1) {
        float* s = &Mrg[lane * 36];
        s[0] = m_r[0]; s[1] = m_r[1];
        s[2] = l_l[0]; s[3] = l_l[1];
        #pragma unroll
        for (int qf = 0; qf < 2; qf++)
            #pragma unroll
            for (int ch = 0; ch < 4; ch++)
                #pragma unroll
                for (int r = 0; r < 4; r++)
                    s[4 + qf * 16 + ch * 4 + r] = o[qf][ch][r];
    }
    __syncthreads();
    if (ws == 0) {
        const float* s = &Mrg[lane * 36];
        #pragma unroll
        for (int qf = 0; qf < 2; qf++) {
            float m1 = s[qf], l1 = s[2 + qf];
            float mM = fmaxf(m_r[qf], m1);
            float a0 = exp2f(m_r[qf] - mM);
            float a1 = exp2f(m1 - mM);
            float lt = a0 * l_l[qf] + a1 * l1;
            float rl = 1.0f / lt;
            const int t = q0 + qf * 16 + cc;
            #pragma unroll
            for (int ch = 0; ch < 4; ch++) {
                bf16x4 ov;
                #pragma unroll
                for (int r = 0; r < 4; r++) {
                    float m0v = o[qf][ch][r] * a0 + s[4 + qf * 16 + ch * 4 + r] * a1;
                    ov[r] = f2bs(m0v * rl);
                }
                *(bf16x4*)(Aout + ((size_t)b * 2048 + t) * 1024 + h * 64 + ch * 16 + g * 4) = ov;
            }
        }
    }
}

// ---------------------------------------------------------------------------
// Kernel 3: projection. 128x64 tile (512 blocks = 2/CU).
// ---------------------------------------------------------------------------
__global__ __launch_bounds__(256) void proj_gemm(
    const short* __restrict__ A, const short* __restrict__ Wt,
    const float* __restrict__ bias, float* __restrict__ Out)
{
    __shared__ short Al[128 * 64];
    __shared__ short Bl[64 * 64];
    const int tid  = threadIdx.x;
    const int lane = tid & 63;
    const int wid  = tid >> 6;
    const int wm = wid >> 1, wn = wid & 1;
    const int g = lane >> 4, cc = lane & 15;
    const int m0 = blockIdx.y * 128, n0 = blockIdx.x * 64;

    f32x4 acc[4][2];
    const f32x4 z4 = {0.f, 0.f, 0.f, 0.f};
    #pragma unroll
    for (int i = 0; i < 4; i++)
        #pragma unroll
        for (int j = 0; j < 2; j++) acc[i][j] = z4;

    for (int k0 = 0; k0 < 1024; k0 += 64) {
        #pragma unroll
        for (int i = 0; i < 4; i++) {
            int chunk = (wid * 4 + i) * 64 + lane;
            int row = chunk >> 3, c = chunk & 7;
            GLOAD_LDS16(A + (size_t)(m0 + row) * 1024 + k0 + c * 8, &Al[chunk * 8]);
        }
        #pragma unroll
        for (int i = 0; i < 2; i++) {
            int chunk = (wid * 2 + i) * 64 + lane;
            int row = chunk >> 3, c = chunk & 7;
            GLOAD_LDS16(Wt + (size_t)(n0 + row) * 1024 + k0 + c * 8, &Bl[chunk * 8]);
        }
        __syncthreads();

        #pragma unroll
        for (int kk = 0; kk < 2; kk++) {
            bf16x8 af[4], bfv[2];
            #pragma unroll
            for (int m = 0; m < 4; m++)
                af[m] = *(const bf16x8*)&Al[(wm * 64 + m * 16 + cc) * 64 + kk * 32 + g * 8];
            #pragma unroll
            for (int n = 0; n < 2; n++)
                bfv[n] = *(const bf16x8*)&Bl[(wn * 32 + n * 16 + cc) * 64 + kk * 32 + g * 8];
            #pragma unroll
            for (int m = 0; m < 4; m++)
                #pragma unroll
                for (int n = 0; n < 2; n++)
                    acc[m][n] = __builtin_amdgcn_mfma_f32_16x16x32_bf16(af[m], bfv[n], acc[m][n], 0, 0, 0);
        }
        __syncthreads();
    }

    #pragma unroll
    for (int n = 0; n < 2; n++) {
        int col = n0 + wn * 32 + n * 16 + cc;
        float bv = bias[col];
        #pragma unroll
        for (int m = 0; m < 4; m++) {
            #pragma unroll
            for (int r = 0; r < 4; r++) {
                int row = m0 + wm * 64 + m * 16 + g * 4 + r;
                Out[(size_t)row * 1024 + col] = acc[m][n][r] + bv;
            }
        }
    }
}

// ---------------------------------------------------------------------------
extern "C" void kernel_launch(void* const* d_in, const int* in_sizes, int n_in,
                              void* d_out, int out_size, void* d_ws, size_t ws_size,
                              hipStream_t stream)
{
    const float* x      = (const float*)d_in[0];
    const float* W_attn = (const float*)d_in[1];
    const float* b_attn = (const float*)d_in[2];
    const float* W_proj = (const float*)d_in[3];
    const float* b_proj = (const float*)d_in[4];
    float* out = (float*)d_out;

    const size_t SZ = (size_t)4096 * 1024;
    short* R1 = (short*)d_ws;                  // Wt_attn, later Aout
    short* Qw = R1 + SZ;                       // later Wt_proj
    short* Kw = Qw + SZ;
    short* Vt = Kw + SZ;

    short* Wt_attn = R1;
    short* Aout    = R1;
    short* Wt_proj = Qw;
    short* Xb      = (short*)d_out;            // d_out as bf16 scratch until proj

    convx<<<dim3(2048), 256, 0, stream>>>(x, Xb);
    convt<<<dim3(48, 16), 256, 0, stream>>>(W_attn, Wt_attn, 1024, 3072);
    qkv_gemm<<<dim3(256), 512, 0, stream>>>(Xb, Wt_attn, b_attn, Qw, Kw, Vt);
    attn_v7<<<dim3(2048), 128, 0, stream>>>(Qw, Kw, Vt, Aout);
    convt<<<dim3(16, 16), 256, 0, stream>>>(W_proj, Wt_proj, 1024, 1024);
    proj_gemm<<<dim3(16, 32), 256, 0, stream>>>(Aout, Wt_proj, b_proj, out);
}

// Round 9
// 152.538 us; speedup vs baseline: 1.3486x; 1.3486x over previous
//
#include <hip/hip_runtime.h>
#include <hip/hip_bf16.h>

// B=2, T=2048, C=1024, H=16, D=64
// convx(X) -> convt(W_attn) -> qkv_gemm (256x192 8-wave counted-vmcnt) ->
// attn_v7b (2-way KV-split + merge, NO vgpr cap) -> convt(W_proj) -> proj_gemm

typedef __attribute__((ext_vector_type(8))) short bf16x8;
typedef __attribute__((ext_vector_type(4))) short bf16x4;
typedef __attribute__((ext_vector_type(4))) float f32x4;

__device__ __forceinline__ short f2bs(float f) {
    union { __hip_bfloat16 h; short s; } u;
    u.h = __float2bfloat16(f);
    return u.s;
}

#define GLOAD_LDS16(gp, lp)                                                        \
    __builtin_amdgcn_global_load_lds((const __attribute__((address_space(1))) void*)(gp), \
                                     (__attribute__((address_space(3))) void*)(lp), 16, 0, 0)

// ---------------------------------------------------------------------------
// convx: X f32 [4096*1024] -> bf16.
// ---------------------------------------------------------------------------
__global__ __launch_bounds__(256) void convx(
    const float* __restrict__ X, short* __restrict__ Xb)
{
    const size_t i = ((size_t)blockIdx.x * 256 + threadIdx.x) * 8;
    float4 a = *(const float4*)(X + i);
    float4 b = *(const float4*)(X + i + 4);
    bf16x8 s;
    s[0] = f2bs(a.x); s[1] = f2bs(a.y); s[2] = f2bs(a.z); s[3] = f2bs(a.w);
    s[4] = f2bs(b.x); s[5] = f2bs(b.y); s[6] = f2bs(b.z); s[7] = f2bs(b.w);
    *(bf16x8*)(Xb + i) = s;
}

// ---------------------------------------------------------------------------
// convert + transpose: W f32 [K][N] -> Wt bf16 [N][K].
// ---------------------------------------------------------------------------
__global__ __launch_bounds__(256) void convt(
    const float* __restrict__ W, short* __restrict__ Wt, int K, int N)
{
    __shared__ short t[64 * 72];
    const int tid = threadIdx.x;
    const int n0 = blockIdx.x * 64, k0 = blockIdx.y * 64;
    #pragma unroll
    for (int i = 0; i < 4; i++) {
        int k = (tid >> 4) + i * 16;
        int n = (tid & 15) * 4;
        float4 v = *(const float4*)(W + (size_t)(k0 + k) * N + n0 + n);
        t[(n + 0) * 72 + k] = f2bs(v.x);
        t[(n + 1) * 72 + k] = f2bs(v.y);
        t[(n + 2) * 72 + k] = f2bs(v.z);
        t[(n + 3) * 72 + k] = f2bs(v.w);
    }
    __syncthreads();
    #pragma unroll
    for (int i = 0; i < 2; i++) {
        int n  = (tid >> 3) + i * 32;
        int kc = (tid & 7) * 8;
        bf16x8 v = *(const bf16x8*)&t[n * 72 + kc];
        *(bf16x8*)(Wt + (size_t)(n0 + n) * K + k0 + kc) = v;
    }
}

// ---------------------------------------------------------------------------
// Kernel 1: QKV GEMM, 256x192 tile, BK=64, 8 waves, double-buffered LDS with
// counted vmcnt, swizzled reads, setprio.
// ---------------------------------------------------------------------------
__global__ __launch_bounds__(512) void qkv_gemm(
    const short* __restrict__ Xb, const short* __restrict__ Wt,
    const float* __restrict__ bias,
    short* __restrict__ Qw, short* __restrict__ Kw, short* __restrict__ Vt)
{
    __shared__ short Alds[2][256 * 64];
    __shared__ short Blds[2][192 * 64];
    const int tid  = threadIdx.x;
    const int lane = tid & 63;
    const int wid  = tid >> 6;
    const int wm = wid >> 2, wn = wid & 3;
    const int g = lane >> 4, cc = lane & 15;
    const int sw = cc & 7;

    const int bid  = blockIdx.x;
    const int wgid = (bid & 7) * 32 + (bid >> 3);
    const int n0 = (wgid >> 4) * 192;
    const int m0 = (wgid & 15) * 256;

    f32x4 acc[8][3];
    const f32x4 z4 = {0.f, 0.f, 0.f, 0.f};
    #pragma unroll
    for (int i = 0; i < 8; i++)
        #pragma unroll
        for (int j = 0; j < 3; j++) acc[i][j] = z4;

    auto STAGE = [&](int t, int buf) {
        const int k0 = t * 64;
        #pragma unroll
        for (int j = 0; j < 4; j++) {
            int c = j * 512 + wid * 64 + lane;
            int row = c >> 3, sch = (c & 7) ^ (row & 7);
            GLOAD_LDS16(Xb + (size_t)(m0 + row) * 1024 + k0 + sch * 8,
                        &Alds[buf][c * 8]);
        }
        #pragma unroll
        for (int j = 0; j < 3; j++) {
            int c = j * 512 + wid * 64 + lane;
            int row = c >> 3, sch = (c & 7) ^ (row & 7);
            GLOAD_LDS16(Wt + (size_t)(n0 + row) * 1024 + k0 + sch * 8,
                        &Blds[buf][c * 8]);
        }
    };

    STAGE(0, 0);
    STAGE(1, 1);
    asm volatile("s_waitcnt vmcnt(7)" ::: "memory");
    asm volatile("s_barrier" ::: "memory");

    const int NT = 16;
    for (int t = 0; t < NT; t++) {
        const short* Ab = Alds[t & 1];
        const short* Bb = Blds[t & 1];

        bf16x8 bfr[3][2];
        #pragma unroll
        for (int nf = 0; nf < 3; nf++)
            #pragma unroll
            for (int kk = 0; kk < 2; kk++)
                bfr[nf][kk] = *(const bf16x8*)&Bb[(wn * 48 + nf * 16 + cc) * 64 +
                                                  ((kk * 4 + g) ^ sw) * 8];
        {
            bf16x8 af[4][2];
            #pragma unroll
            for (int mf = 0; mf < 4; mf++)
                #pragma unroll
                for (int kk = 0; kk < 2; kk++)
                    af[mf][kk] = *(const bf16x8*)&Ab[(wm * 128 + mf * 16 + cc) * 64 +
                                                     ((kk * 4 + g) ^ sw) * 8];
            __builtin_amdgcn_s_setprio(1);
            #pragma unroll
            for (int mf = 0; mf < 4; mf++)
                #pragma unroll
                for (int nf = 0; nf < 3; nf++)
                    #pragma unroll
                    for (int kk = 0; kk < 2; kk++)
                        acc[mf][nf] = __builtin_amdgcn_mfma_f32_16x16x32_bf16(
                            af[mf][kk], bfr[nf][kk], acc[mf][nf], 0, 0, 0);
            __builtin_amdgcn_s_setprio(0);
        }
        {
            bf16x8 af[4][2];
            #pragma unroll
            for (int mf = 0; mf < 4; mf++)
                #pragma unroll
                for (int kk = 0; kk < 2; kk++)
                    af[mf][kk] = *(const bf16x8*)&Ab[(wm * 128 + (mf + 4) * 16 + cc) * 64 +
                                                     ((kk * 4 + g) ^ sw) * 8];
            __builtin_amdgcn_s_setprio(1);
            #pragma unroll
            for (int mf = 0; mf < 4; mf++)
                #pragma unroll
                for (int nf = 0; nf < 3; nf++)
                    #pragma unroll
                    for (int kk = 0; kk < 2; kk++)
                        acc[mf + 4][nf] = __builtin_amdgcn_mfma_f32_16x16x32_bf16(
                            af[mf][kk], bfr[nf][kk], acc[mf + 4][nf], 0, 0, 0);
            __builtin_amdgcn_s_setprio(0);
        }

        asm volatile("s_barrier" ::: "memory");
        if (t + 2 < NT) {
            STAGE(t + 2, t & 1);
            asm volatile("s_waitcnt vmcnt(7)" ::: "memory");
            asm volatile("s_barrier" ::: "memory");
        } else if (t + 1 < NT) {
            asm volatile("s_waitcnt vmcnt(0)" ::: "memory");
            asm volatile("s_barrier" ::: "memory");
        }
    }

    const float QSCALE = 0.04508422976f;
    #pragma unroll
    for (int nf = 0; nf < 3; nf++) {
        int col = n0 + wn * 48 + nf * 16 + cc;
        int which = col >> 10;
        int ci = col & 1023;
        int h = ci >> 6, d = ci & 63;
        float bv = bias[col];
        #pragma unroll
        for (int mf = 0; mf < 8; mf++) {
            #pragma unroll
            for (int r = 0; r < 4; r++) {
                int row = m0 + wm * 128 + mf * 16 + g * 4 + r;
                int b = row >> 11, tt = row & 2047;
                int bh = b * 16 + h;
                float v = acc[mf][nf][r] + bv;
                if (which == 0)      Qw[((size_t)bh * 2048 + tt) * 64 + d] = f2bs(v * QSCALE);
                else if (which == 1) Kw[((size_t)bh * 2048 + tt) * 64 + d] = f2bs(v);
                else {
                    int tp = (tt & ~31) | (((tt >> 2) & 3) * 8 + ((tt >> 4) & 1) * 4 + (tt & 3));
                    Vt[((size_t)bh * 64 + d) * 2048 + tp] = f2bs(v);
                }
            }
        }
    }
}

// ---------------------------------------------------------------------------
// Kernel 2: causal flash attention v7b. 128-thr block = 2 waves on ONE 32-row
// q-tile; wave s handles KV-steps st ≡ s (mod 2); merge at end.
// NO launch_bounds min-waves (r8 lesson: (128,4) capped VGPR at 64 -> 150MB
// scratch spill traffic).
// ---------------------------------------------------------------------------
#define ATTN_STEP(KF, VF, KN, VN, KVN, PRE, MSK, KV0)                             \
  {                                                                               \
    if (PRE) {                                                                    \
      _Pragma("unroll") for (int kvc = 0; kvc < 2; kvc++)                         \
      _Pragma("unroll") for (int ds = 0; ds < 2; ds++)                            \
        KN[kvc * 2 + ds] = *(const bf16x8*)(Kb + ((KVN) + kvc * 16 + cc) * 64 + ds * 32 + g * 8); \
      _Pragma("unroll") for (int ch = 0; ch < 4; ch++)                            \
        VN[ch] = *(const bf16x8*)(Vb + (ch * 16 + cc) * 2048 + (KVN) + g * 8);     \
    }                                                                             \
    f32x4 s_[2][2];                                                               \
    _Pragma("unroll") for (int qf = 0; qf < 2; qf++)                              \
    _Pragma("unroll") for (int kvc = 0; kvc < 2; kvc++) {                         \
      s_[qf][kvc] = z4;                                                           \
      _Pragma("unroll") for (int ds = 0; ds < 2; ds++)                            \
        s_[qf][kvc] = __builtin_amdgcn_mfma_f32_16x16x32_bf16(                    \
            KF[kvc * 2 + ds], qfr[qf][ds], s_[qf][kvc], 0, 0, 0);                 \
    }                                                                             \
    bf16x8 pb_[2];                                                                \
    _Pragma("unroll") for (int qf = 0; qf < 2; qf++) {                            \
      float sv[8];                                                                \
      _Pragma("unroll") for (int kvc = 0; kvc < 2; kvc++)                         \
      _Pragma("unroll") for (int r = 0; r < 4; r++) {                             \
        float v = s_[qf][kvc][r];                                                 \
        if (MSK) {                                                                \
          int kv = (KV0) + kvc * 16 + g * 4 + r;                                  \
          v = (kv <= q0 + qf * 16 + cc) ? v : -1e30f;                             \
        }                                                                         \
        sv[kvc * 4 + r] = v;                                                      \
      }                                                                           \
      float lm = fmaxf(fmaxf(fmaxf(sv[0], sv[1]), fmaxf(sv[2], sv[3])),           \
                       fmaxf(fmaxf(sv[4], sv[5]), fmaxf(sv[6], sv[7])));          \
      if (__any(lm > m_r[qf] + 6.0f)) {                                           \
        float mx = lm;                                                            \
        mx = fmaxf(mx, __shfl_xor(mx, 16));                                       \
        mx = fmaxf(mx, __shfl_xor(mx, 32));                                       \
        float mn = fmaxf(m_r[qf], mx);                                            \
        float a = exp2f(m_r[qf] - mn);                                            \
        _Pragma("unroll") for (int ch = 0; ch < 4; ch++)                          \
        _Pragma("unroll") for (int r = 0; r < 4; r++) o[qf][ch][r] *= a;          \
        l_l[qf] *= a;                                                             \
        m_r[qf] = mn;                                                             \
      }                                                                           \
      float rs = 0.f;                                                             \
      _Pragma("unroll") for (int i = 0; i < 8; i++) {                             \
        float p = exp2f(sv[i] - m_r[qf]);                                         \
        pb_[qf][i] = f2bs(p);                                                     \
        rs += p;                                                                  \
      }                                                                           \
      l_l[qf] += rs;                                                              \
    }                                                                             \
    _Pragma("unroll") for (int ch = 0; ch < 4; ch++) {                            \
      o[0][ch] = __builtin_amdgcn_mfma_f32_16x16x32_bf16(VF[ch], pb_[0], o[0][ch], 0, 0, 0); \
      o[1][ch] = __builtin_amdgcn_mfma_f32_16x16x32_bf16(VF[ch], pb_[1], o[1][ch], 0, 0, 0); \
    }                                                                             \
  }

__global__ __launch_bounds__(128) void attn_v7b(
    const short* __restrict__ Qw, const short* __restrict__ Kw,
    const short* __restrict__ Vt, short* __restrict__ Aout)
{
    __shared__ float Mrg[64 * 36];        // wave1's state: m[2], l[2], o[32]
    const int tid  = threadIdx.x;
    const int lane = tid & 63;
    const int ws   = tid >> 6;            // KV-split index 0/1
    const int g = lane >> 4, cc = lane & 15;
    const int bid = blockIdx.x;
    const int qt = 63 - (bid >> 5);       // longest tiles first
    const int bh = bid & 31;              // XCD = bh % 8
    const int q0 = qt * 32;
    const int b = bh >> 4, h = bh & 15;
    const short* Qb = Qw + (size_t)bh * 2048 * 64;
    const short* Kb = Kw + (size_t)bh * 2048 * 64;
    const short* Vb = Vt + (size_t)bh * 64 * 2048;

    bf16x8 qfr[2][2];
    #pragma unroll
    for (int qf = 0; qf < 2; qf++)
        #pragma unroll
        for (int ds = 0; ds < 2; ds++)
            qfr[qf][ds] = *(const bf16x8*)(Qb + (q0 + qf * 16 + cc) * 64 + ds * 32 + g * 8);

    const f32x4 z4 = {0.f, 0.f, 0.f, 0.f};
    f32x4 o[2][4];
    #pragma unroll
    for (int qf = 0; qf < 2; qf++)
        #pragma unroll
        for (int ch = 0; ch < 4; ch++) o[qf][ch] = z4;
    float m_r[2] = {-1e30f, -1e30f};
    float l_l[2] = {0.f, 0.f};

    const int lastSt = qt - ((qt ^ ws) & 1);
    const bool active = (lastSt >= ws);

    if (active) {
        bf16x8 kA[4], vA[4], kB[4], vB[4];
        const int kvS = ws * 32;
        #pragma unroll
        for (int kvc = 0; kvc < 2; kvc++)
            #pragma unroll
            for (int ds = 0; ds < 2; ds++)
                kA[kvc * 2 + ds] = *(const bf16x8*)(Kb + (kvS + kvc * 16 + cc) * 64 + ds * 32 + g * 8);
        #pragma unroll
        for (int ch = 0; ch < 4; ch++)
            vA[ch] = *(const bf16x8*)(Vb + (ch * 16 + cc) * 2048 + kvS + g * 8);

        int st = ws;
        const int mk = (lastSt == qt);
        while (st + 4 <= lastSt) {
            ATTN_STEP(kA, vA, kB, vB, (st + 2) * 32, 1, 0, 0);
            ATTN_STEP(kB, vB, kA, vA, (st + 4) * 32, 1, 0, 0);
            st += 4;
        }
        if (st + 2 <= lastSt) {
            ATTN_STEP(kA, vA, kB, vB, (st + 2) * 32, 1, 0, 0);
            ATTN_STEP(kB, vB, kB, vB, 0, 0, mk, lastSt * 32);
        } else {
            ATTN_STEP(kA, vA, kA, vA, 0, 0, mk, lastSt * 32);
        }
    }

    // per-wave l reduction across g-groups
    #pragma unroll
    for (int qf = 0; qf < 2; qf++) {
        float lt = l_l[qf];
        lt += __shfl_xor(lt, 16);
        lt += __shfl_xor(lt, 32);
        l_l[qf] = lt;
    }

    // merge the two KV-split halves
    if (ws == 1) {
        float* s = &Mrg[lane * 36];
        s[0] = m_r[0]; s[1] = m_r[1];
        s[2] = l_l[0]; s[3] = l_l[1];
        #pragma unroll
        for (int qf = 0; qf < 2; qf++)
            #pragma unroll
            for (int ch = 0; ch < 4; ch++)
                #pragma unroll
                for (int r = 0; r < 4; r++)
                    s[4 + qf * 16 + ch * 4 + r] = o[qf][ch][r];
    }
    __syncthreads();
    if (ws == 0) {
        const float* s = &Mrg[lane * 36];
        #pragma unroll
        for (int qf = 0; qf < 2; qf++) {
            float m1 = s[qf], l1 = s[2 + qf];
            float mM = fmaxf(m_r[qf], m1);
            float a0 = exp2f(m_r[qf] - mM);
            float a1 = exp2f(m1 - mM);
            float lt = a0 * l_l[qf] + a1 * l1;
            float rl = 1.0f / lt;
            const int t = q0 + qf * 16 + cc;
            #pragma unroll
            for (int ch = 0; ch < 4; ch++) {
                bf16x4 ov;
                #pragma unroll
                for (int r = 0; r < 4; r++) {
                    float m0v = o[qf][ch][r] * a0 + s[4 + qf * 16 + ch * 4 + r] * a1;
                    ov[r] = f2bs(m0v * rl);
                }
                *(bf16x4*)(Aout + ((size_t)b * 2048 + t) * 1024 + h * 64 + ch * 16 + g * 4) = ov;
            }
        }
    }
}

// ---------------------------------------------------------------------------
// Kernel 3: projection. 128x64 tile (512 blocks = 2/CU).
// ---------------------------------------------------------------------------
__global__ __launch_bounds__(256) void proj_gemm(
    const short* __restrict__ A, const short* __restrict__ Wt,
    const float* __restrict__ bias, float* __restrict__ Out)
{
    __shared__ short Al[128 * 64];
    __shared__ short Bl[64 * 64];
    const int tid  = threadIdx.x;
    const int lane = tid & 63;
    const int wid  = tid >> 6;
    const int wm = wid >> 1, wn = wid & 1;
    const int g = lane >> 4, cc = lane & 15;
    const int m0 = blockIdx.y * 128, n0 = blockIdx.x * 64;

    f32x4 acc[4][2];
    const f32x4 z4 = {0.f, 0.f, 0.f, 0.f};
    #pragma unroll
    for (int i = 0; i < 4; i++)
        #pragma unroll
        for (int j = 0; j < 2; j++) acc[i][j] = z4;

    for (int k0 = 0; k0 < 1024; k0 += 64) {
        #pragma unroll
        for (int i = 0; i < 4; i++) {
            int chunk = (wid * 4 + i) * 64 + lane;
            int row = chunk >> 3, c = chunk & 7;
            GLOAD_LDS16(A + (size_t)(m0 + row) * 1024 + k0 + c * 8, &Al[chunk * 8]);
        }
        #pragma unroll
        for (int i = 0; i < 2; i++) {
            int chunk = (wid * 2 + i) * 64 + lane;
            int row = chunk >> 3, c = chunk & 7;
            GLOAD_LDS16(Wt + (size_t)(n0 + row) * 1024 + k0 + c * 8, &Bl[chunk * 8]);
        }
        __syncthreads();

        #pragma unroll
        for (int kk = 0; kk < 2; kk++) {
            bf16x8 af[4], bfv[2];
            #pragma unroll
            for (int m = 0; m < 4; m++)
                af[m] = *(const bf16x8*)&Al[(wm * 64 + m * 16 + cc) * 64 + kk * 32 + g * 8];
            #pragma unroll
            for (int n = 0; n < 2; n++)
                bfv[n] = *(const bf16x8*)&Bl[(wn * 32 + n * 16 + cc) * 64 + kk * 32 + g * 8];
            #pragma unroll
            for (int m = 0; m < 4; m++)
                #pragma unroll
                for (int n = 0; n < 2; n++)
                    acc[m][n] = __builtin_amdgcn_mfma_f32_16x16x32_bf16(af[m], bfv[n], acc[m][n], 0, 0, 0);
        }
        __syncthreads();
    }

    #pragma unroll
    for (int n = 0; n < 2; n++) {
        int col = n0 + wn * 32 + n * 16 + cc;
        float bv = bias[col];
        #pragma unroll
        for (int m = 0; m < 4; m++) {
            #pragma unroll
            for (int r = 0; r < 4; r++) {
                int row = m0 + wm * 64 + m * 16 + g * 4 + r;
                Out[(size_t)row * 1024 + col] = acc[m][n][r] + bv;
            }
        }
    }
}

// ---------------------------------------------------------------------------
extern "C" void kernel_launch(void* const* d_in, const int* in_sizes, int n_in,
                              void* d_out, int out_size, void* d_ws, size_t ws_size,
                              hipStream_t stream)
{
    const float* x      = (const float*)d_in[0];
    const float* W_attn = (const float*)d_in[1];
    const float* b_attn = (const float*)d_in[2];
    const float* W_proj = (const float*)d_in[3];
    const float* b_proj = (const float*)d_in[4];
    float* out = (float*)d_out;

    const size_t SZ = (size_t)4096 * 1024;
    short* R1 = (short*)d_ws;                  // Wt_attn, later Aout
    short* Qw = R1 + SZ;                       // later Wt_proj
    short* Kw = Qw + SZ;
    short* Vt = Kw + SZ;

    short* Wt_attn = R1;
    short* Aout    = R1;
    short* Wt_proj = Qw;
    short* Xb      = (short*)d_out;            // d_out as bf16 scratch until proj

    convx<<<dim3(2048), 256, 0, stream>>>(x, Xb);
    convt<<<dim3(48, 16), 256, 0, stream>>>(W_attn, Wt_attn, 1024, 3072);
    qkv_gemm<<<dim3(256), 512, 0, stream>>>(Xb, Wt_attn, b_attn, Qw, Kw, Vt);
    attn_v7b<<<dim3(2048), 128, 0, stream>>>(Qw, Kw, Vt, Aout);
    convt<<<dim3(16, 16), 256, 0, stream>>>(W_proj, Wt_proj, 1024, 1024);
    proj_gemm<<<dim3(16, 32), 256, 0, stream>>>(Aout, Wt_proj, b_proj, out);
}

// Round 10
// 151.370 us; speedup vs baseline: 1.3590x; 1.0077x over previous
//
#include <hip/hip_runtime.h>
#include <hip/hip_bf16.h>

// B=2, T=2048, C=1024, H=16, D=64
// convx(X) -> convt(W_attn) -> qkv_gemm (256x192 8-wave counted-vmcnt) ->
// attn_v7c (4-way KV-split + merge) -> convt(W_proj) -> proj_gemm

typedef __attribute__((ext_vector_type(8))) short bf16x8;
typedef __attribute__((ext_vector_type(4))) short bf16x4;
typedef __attribute__((ext_vector_type(4))) float f32x4;

__device__ __forceinline__ short f2bs(float f) {
    union { __hip_bfloat16 h; short s; } u;
    u.h = __float2bfloat16(f);
    return u.s;
}

#define GLOAD_LDS16(gp, lp)                                                        \
    __builtin_amdgcn_global_load_lds((const __attribute__((address_space(1))) void*)(gp), \
                                     (__attribute__((address_space(3))) void*)(lp), 16, 0, 0)

// ---------------------------------------------------------------------------
// convx: X f32 [4096*1024] -> bf16.
// ---------------------------------------------------------------------------
__global__ __launch_bounds__(256) void convx(
    const float* __restrict__ X, short* __restrict__ Xb)
{
    const size_t i = ((size_t)blockIdx.x * 256 + threadIdx.x) * 8;
    float4 a = *(const float4*)(X + i);
    float4 b = *(const float4*)(X + i + 4);
    bf16x8 s;
    s[0] = f2bs(a.x); s[1] = f2bs(a.y); s[2] = f2bs(a.z); s[3] = f2bs(a.w);
    s[4] = f2bs(b.x); s[5] = f2bs(b.y); s[6] = f2bs(b.z); s[7] = f2bs(b.w);
    *(bf16x8*)(Xb + i) = s;
}

// ---------------------------------------------------------------------------
// convert + transpose: W f32 [K][N] -> Wt bf16 [N][K].
// ---------------------------------------------------------------------------
__global__ __launch_bounds__(256) void convt(
    const float* __restrict__ W, short* __restrict__ Wt, int K, int N)
{
    __shared__ short t[64 * 72];
    const int tid = threadIdx.x;
    const int n0 = blockIdx.x * 64, k0 = blockIdx.y * 64;
    #pragma unroll
    for (int i = 0; i < 4; i++) {
        int k = (tid >> 4) + i * 16;
        int n = (tid & 15) * 4;
        float4 v = *(const float4*)(W + (size_t)(k0 + k) * N + n0 + n);
        t[(n + 0) * 72 + k] = f2bs(v.x);
        t[(n + 1) * 72 + k] = f2bs(v.y);
        t[(n + 2) * 72 + k] = f2bs(v.z);
        t[(n + 3) * 72 + k] = f2bs(v.w);
    }
    __syncthreads();
    #pragma unroll
    for (int i = 0; i < 2; i++) {
        int n  = (tid >> 3) + i * 32;
        int kc = (tid & 7) * 8;
        bf16x8 v = *(const bf16x8*)&t[n * 72 + kc];
        *(bf16x8*)(Wt + (size_t)(n0 + n) * K + k0 + kc) = v;
    }
}

// ---------------------------------------------------------------------------
// Kernel 1: QKV GEMM, 256x192 tile, BK=64, 8 waves, double-buffered LDS with
// counted vmcnt, swizzled reads, setprio.
// ---------------------------------------------------------------------------
__global__ __launch_bounds__(512) void qkv_gemm(
    const short* __restrict__ Xb, const short* __restrict__ Wt,
    const float* __restrict__ bias,
    short* __restrict__ Qw, short* __restrict__ Kw, short* __restrict__ Vt)
{
    __shared__ short Alds[2][256 * 64];
    __shared__ short Blds[2][192 * 64];
    const int tid  = threadIdx.x;
    const int lane = tid & 63;
    const int wid  = tid >> 6;
    const int wm = wid >> 2, wn = wid & 3;
    const int g = lane >> 4, cc = lane & 15;
    const int sw = cc & 7;

    const int bid  = blockIdx.x;
    const int wgid = (bid & 7) * 32 + (bid >> 3);
    const int n0 = (wgid >> 4) * 192;
    const int m0 = (wgid & 15) * 256;

    f32x4 acc[8][3];
    const f32x4 z4 = {0.f, 0.f, 0.f, 0.f};
    #pragma unroll
    for (int i = 0; i < 8; i++)
        #pragma unroll
        for (int j = 0; j < 3; j++) acc[i][j] = z4;

    auto STAGE = [&](int t, int buf) {
        const int k0 = t * 64;
        #pragma unroll
        for (int j = 0; j < 4; j++) {
            int c = j * 512 + wid * 64 + lane;
            int row = c >> 3, sch = (c & 7) ^ (row & 7);
            GLOAD_LDS16(Xb + (size_t)(m0 + row) * 1024 + k0 + sch * 8,
                        &Alds[buf][c * 8]);
        }
        #pragma unroll
        for (int j = 0; j < 3; j++) {
            int c = j * 512 + wid * 64 + lane;
            int row = c >> 3, sch = (c & 7) ^ (row & 7);
            GLOAD_LDS16(Wt + (size_t)(n0 + row) * 1024 + k0 + sch * 8,
                        &Blds[buf][c * 8]);
        }
    };

    STAGE(0, 0);
    STAGE(1, 1);
    asm volatile("s_waitcnt vmcnt(7)" ::: "memory");
    asm volatile("s_barrier" ::: "memory");

    const int NT = 16;
    for (int t = 0; t < NT; t++) {
        const short* Ab = Alds[t & 1];
        const short* Bb = Blds[t & 1];

        bf16x8 bfr[3][2];
        #pragma unroll
        for (int nf = 0; nf < 3; nf++)
            #pragma unroll
            for (int kk = 0; kk < 2; kk++)
                bfr[nf][kk] = *(const bf16x8*)&Bb[(wn * 48 + nf * 16 + cc) * 64 +
                                                  ((kk * 4 + g) ^ sw) * 8];
        {
            bf16x8 af[4][2];
            #pragma unroll
            for (int mf = 0; mf < 4; mf++)
                #pragma unroll
                for (int kk = 0; kk < 2; kk++)
                    af[mf][kk] = *(const bf16x8*)&Ab[(wm * 128 + mf * 16 + cc) * 64 +
                                                     ((kk * 4 + g) ^ sw) * 8];
            __builtin_amdgcn_s_setprio(1);
            #pragma unroll
            for (int mf = 0; mf < 4; mf++)
                #pragma unroll
                for (int nf = 0; nf < 3; nf++)
                    #pragma unroll
                    for (int kk = 0; kk < 2; kk++)
                        acc[mf][nf] = __builtin_amdgcn_mfma_f32_16x16x32_bf16(
                            af[mf][kk], bfr[nf][kk], acc[mf][nf], 0, 0, 0);
            __builtin_amdgcn_s_setprio(0);
        }
        {
            bf16x8 af[4][2];
            #pragma unroll
            for (int mf = 0; mf < 4; mf++)
                #pragma unroll
                for (int kk = 0; kk < 2; kk++)
                    af[mf][kk] = *(const bf16x8*)&Ab[(wm * 128 + (mf + 4) * 16 + cc) * 64 +
                                                     ((kk * 4 + g) ^ sw) * 8];
            __builtin_amdgcn_s_setprio(1);
            #pragma unroll
            for (int mf = 0; mf < 4; mf++)
                #pragma unroll
                for (int nf = 0; nf < 3; nf++)
                    #pragma unroll
                    for (int kk = 0; kk < 2; kk++)
                        acc[mf + 4][nf] = __builtin_amdgcn_mfma_f32_16x16x32_bf16(
                            af[mf][kk], bfr[nf][kk], acc[mf + 4][nf], 0, 0, 0);
            __builtin_amdgcn_s_setprio(0);
        }

        asm volatile("s_barrier" ::: "memory");
        if (t + 2 < NT) {
            STAGE(t + 2, t & 1);
            asm volatile("s_waitcnt vmcnt(7)" ::: "memory");
            asm volatile("s_barrier" ::: "memory");
        } else if (t + 1 < NT) {
            asm volatile("s_waitcnt vmcnt(0)" ::: "memory");
            asm volatile("s_barrier" ::: "memory");
        }
    }

    const float QSCALE = 0.04508422976f;
    #pragma unroll
    for (int nf = 0; nf < 3; nf++) {
        int col = n0 + wn * 48 + nf * 16 + cc;
        int which = col >> 10;
        int ci = col & 1023;
        int h = ci >> 6, d = ci & 63;
        float bv = bias[col];
        #pragma unroll
        for (int mf = 0; mf < 8; mf++) {
            #pragma unroll
            for (int r = 0; r < 4; r++) {
                int row = m0 + wm * 128 + mf * 16 + g * 4 + r;
                int b = row >> 11, tt = row & 2047;
                int bh = b * 16 + h;
                float v = acc[mf][nf][r] + bv;
                if (which == 0)      Qw[((size_t)bh * 2048 + tt) * 64 + d] = f2bs(v * QSCALE);
                else if (which == 1) Kw[((size_t)bh * 2048 + tt) * 64 + d] = f2bs(v);
                else {
                    int tp = (tt & ~31) | (((tt >> 2) & 3) * 8 + ((tt >> 4) & 1) * 4 + (tt & 3));
                    Vt[((size_t)bh * 64 + d) * 2048 + tp] = f2bs(v);
                }
            }
        }
    }
}

// ---------------------------------------------------------------------------
// Kernel 2: causal flash attention v7c. 256-thr block = 4 waves on ONE 32-row
// q-tile; wave ws handles KV-steps st ≡ ws (mod 4); 4-state merge at end.
// 8192 waves over 4096 VGPR-limited slots -> scheduler backfill keeps
// occupancy near cap (fixes v7b's zero-backfill decay).
// ---------------------------------------------------------------------------
#define ATTN_STEP(KF, VF, KN, VN, KVN, PRE, MSK, KV0)                             \
  {                                                                               \
    if (PRE) {                                                                    \
      _Pragma("unroll") for (int kvc = 0; kvc < 2; kvc++)                         \
      _Pragma("unroll") for (int ds = 0; ds < 2; ds++)                            \
        KN[kvc * 2 + ds] = *(const bf16x8*)(Kb + ((KVN) + kvc * 16 + cc) * 64 + ds * 32 + g * 8); \
      _Pragma("unroll") for (int ch = 0; ch < 4; ch++)                            \
        VN[ch] = *(const bf16x8*)(Vb + (ch * 16 + cc) * 2048 + (KVN) + g * 8);     \
    }                                                                             \
    f32x4 s_[2][2];                                                               \
    _Pragma("unroll") for (int qf = 0; qf < 2; qf++)                              \
    _Pragma("unroll") for (int kvc = 0; kvc < 2; kvc++) {                         \
      s_[qf][kvc] = z4;                                                           \
      _Pragma("unroll") for (int ds = 0; ds < 2; ds++)                            \
        s_[qf][kvc] = __builtin_amdgcn_mfma_f32_16x16x32_bf16(                    \
            KF[kvc * 2 + ds], qfr[qf][ds], s_[qf][kvc], 0, 0, 0);                 \
    }                                                                             \
    bf16x8 pb_[2];                                                                \
    _Pragma("unroll") for (int qf = 0; qf < 2; qf++) {                            \
      float sv[8];                                                                \
      _Pragma("unroll") for (int kvc = 0; kvc < 2; kvc++)                         \
      _Pragma("unroll") for (int r = 0; r < 4; r++) {                             \
        float v = s_[qf][kvc][r];                                                 \
        if (MSK) {                                                                \
          int kv = (KV0) + kvc * 16 + g * 4 + r;                                  \
          v = (kv <= q0 + qf * 16 + cc) ? v : -1e30f;                             \
        }                                                                         \
        sv[kvc * 4 + r] = v;                                                      \
      }                                                                           \
      float lm = fmaxf(fmaxf(fmaxf(sv[0], sv[1]), fmaxf(sv[2], sv[3])),           \
                       fmaxf(fmaxf(sv[4], sv[5]), fmaxf(sv[6], sv[7])));          \
      if (__any(lm > m_r[qf] + 6.0f)) {                                           \
        float mx = lm;                                                            \
        mx = fmaxf(mx, __shfl_xor(mx, 16));                                       \
        mx = fmaxf(mx, __shfl_xor(mx, 32));                                       \
        float mn = fmaxf(m_r[qf], mx);                                            \
        float a = exp2f(m_r[qf] - mn);                                            \
        _Pragma("unroll") for (int ch = 0; ch < 4; ch++)                          \
        _Pragma("unroll") for (int r = 0; r < 4; r++) o[qf][ch][r] *= a;          \
        l_l[qf] *= a;                                                             \
        m_r[qf] = mn;                                                             \
      }                                                                           \
      float rs = 0.f;                                                             \
      _Pragma("unroll") for (int i = 0; i < 8; i++) {                             \
        float p = exp2f(sv[i] - m_r[qf]);                                         \
        pb_[qf][i] = f2bs(p);                                                     \
        rs += p;                                                                  \
      }                                                                           \
      l_l[qf] += rs;                                                              \
    }                                                                             \
    _Pragma("unroll") for (int ch = 0; ch < 4; ch++) {                            \
      o[0][ch] = __builtin_amdgcn_mfma_f32_16x16x32_bf16(VF[ch], pb_[0], o[0][ch], 0, 0, 0); \
      o[1][ch] = __builtin_amdgcn_mfma_f32_16x16x32_bf16(VF[ch], pb_[1], o[1][ch], 0, 0, 0); \
    }                                                                             \
  }

__global__ __launch_bounds__(256) void attn_v7c(
    const short* __restrict__ Qw, const short* __restrict__ Kw,
    const short* __restrict__ Vt, short* __restrict__ Aout)
{
    __shared__ float Mrg[3 * 64 * 36];    // waves 1..3 state: m[2], l[2], o[32]
    const int tid  = threadIdx.x;
    const int lane = tid & 63;
    const int ws   = tid >> 6;            // KV-split index 0..3
    const int g = lane >> 4, cc = lane & 15;
    const int bid = blockIdx.x;
    const int qt = 63 - (bid >> 5);       // longest tiles first
    const int bh = bid & 31;              // XCD = bh % 8
    const int q0 = qt * 32;
    const int b = bh >> 4, h = bh & 15;
    const short* Qb = Qw + (size_t)bh * 2048 * 64;
    const short* Kb = Kw + (size_t)bh * 2048 * 64;
    const short* Vb = Vt + (size_t)bh * 64 * 2048;

    bf16x8 qfr[2][2];
    #pragma unroll
    for (int qf = 0; qf < 2; qf++)
        #pragma unroll
        for (int ds = 0; ds < 2; ds++)
            qfr[qf][ds] = *(const bf16x8*)(Qb + (q0 + qf * 16 + cc) * 64 + ds * 32 + g * 8);

    const f32x4 z4 = {0.f, 0.f, 0.f, 0.f};
    f32x4 o[2][4];
    #pragma unroll
    for (int qf = 0; qf < 2; qf++)
        #pragma unroll
        for (int ch = 0; ch < 4; ch++) o[qf][ch] = z4;
    float m_r[2] = {-1e30f, -1e30f};
    float l_l[2] = {0.f, 0.f};

    // largest st <= qt with st ≡ ws (mod 4); negative -> inactive
    const int lastSt = qt - ((qt - ws) & 3);
    const bool active = (lastSt >= 0);

    if (active) {
        bf16x8 kA[4], vA[4], kB[4], vB[4];
        const int kvS = ws * 32;
        #pragma unroll
        for (int kvc = 0; kvc < 2; kvc++)
            #pragma unroll
            for (int ds = 0; ds < 2; ds++)
                kA[kvc * 2 + ds] = *(const bf16x8*)(Kb + (kvS + kvc * 16 + cc) * 64 + ds * 32 + g * 8);
        #pragma unroll
        for (int ch = 0; ch < 4; ch++)
            vA[ch] = *(const bf16x8*)(Vb + (ch * 16 + cc) * 2048 + kvS + g * 8);

        int st = ws;
        const int mk = (lastSt == qt);
        while (st + 8 <= lastSt) {
            ATTN_STEP(kA, vA, kB, vB, (st + 4) * 32, 1, 0, 0);
            ATTN_STEP(kB, vB, kA, vA, (st + 8) * 32, 1, 0, 0);
            st += 8;
        }
        if (st + 4 <= lastSt) {
            ATTN_STEP(kA, vA, kB, vB, (st + 4) * 32, 1, 0, 0);
            ATTN_STEP(kB, vB, kB, vB, 0, 0, mk, lastSt * 32);
        } else {
            ATTN_STEP(kA, vA, kA, vA, 0, 0, mk, lastSt * 32);
        }
    }

    // per-wave l reduction across g-groups
    #pragma unroll
    for (int qf = 0; qf < 2; qf++) {
        float lt = l_l[qf];
        lt += __shfl_xor(lt, 16);
        lt += __shfl_xor(lt, 32);
        l_l[qf] = lt;
    }

    // merge the four KV-split quarters
    if (ws != 0) {
        float* s = &Mrg[(ws - 1) * 64 * 36 + lane * 36];
        s[0] = m_r[0]; s[1] = m_r[1];
        s[2] = l_l[0]; s[3] = l_l[1];
        #pragma unroll
        for (int qf = 0; qf < 2; qf++)
            #pragma unroll
            for (int ch = 0; ch < 4; ch++)
                #pragma unroll
                for (int r = 0; r < 4; r++)
                    s[4 + qf * 16 + ch * 4 + r] = o[qf][ch][r];
    }
    __syncthreads();
    if (ws == 0) {
        const float* s1 = &Mrg[0 * 64 * 36 + lane * 36];
        const float* s2 = &Mrg[1 * 64 * 36 + lane * 36];
        const float* s3 = &Mrg[2 * 64 * 36 + lane * 36];
        #pragma unroll
        for (int qf = 0; qf < 2; qf++) {
            float mM = fmaxf(fmaxf(m_r[qf], s1[qf]), fmaxf(s2[qf], s3[qf]));
            float a0 = exp2f(m_r[qf] - mM);
            float a1 = exp2f(s1[qf] - mM);
            float a2 = exp2f(s2[qf] - mM);
            float a3 = exp2f(s3[qf] - mM);
            float lt = a0 * l_l[qf] + a1 * s1[2 + qf] + a2 * s2[2 + qf] + a3 * s3[2 + qf];
            float rl = 1.0f / lt;
            const int t = q0 + qf * 16 + cc;
            #pragma unroll
            for (int ch = 0; ch < 4; ch++) {
                bf16x4 ov;
                #pragma unroll
                for (int r = 0; r < 4; r++) {
                    int idx = 4 + qf * 16 + ch * 4 + r;
                    float m0v = o[qf][ch][r] * a0 + s1[idx] * a1 + s2[idx] * a2 + s3[idx] * a3;
                    ov[r] = f2bs(m0v * rl);
                }
                *(bf16x4*)(Aout + ((size_t)b * 2048 + t) * 1024 + h * 64 + ch * 16 + g * 4) = ov;
            }
        }
    }
}

// ---------------------------------------------------------------------------
// Kernel 3: projection. 128x64 tile (512 blocks = 2/CU).
// ---------------------------------------------------------------------------
__global__ __launch_bounds__(256) void proj_gemm(
    const short* __restrict__ A, const short* __restrict__ Wt,
    const float* __restrict__ bias, float* __restrict__ Out)
{
    __shared__ short Al[128 * 64];
    __shared__ short Bl[64 * 64];
    const int tid  = threadIdx.x;
    const int lane = tid & 63;
    const int wid  = tid >> 6;
    const int wm = wid >> 1, wn = wid & 1;
    const int g = lane >> 4, cc = lane & 15;
    const int m0 = blockIdx.y * 128, n0 = blockIdx.x * 64;

    f32x4 acc[4][2];
    const f32x4 z4 = {0.f, 0.f, 0.f, 0.f};
    #pragma unroll
    for (int i = 0; i < 4; i++)
        #pragma unroll
        for (int j = 0; j < 2; j++) acc[i][j] = z4;

    for (int k0 = 0; k0 < 1024; k0 += 64) {
        #pragma unroll
        for (int i = 0; i < 4; i++) {
            int chunk = (wid * 4 + i) * 64 + lane;
            int row = chunk >> 3, c = chunk & 7;
            GLOAD_LDS16(A + (size_t)(m0 + row) * 1024 + k0 + c * 8, &Al[chunk * 8]);
        }
        #pragma unroll
        for (int i = 0; i < 2; i++) {
            int chunk = (wid * 2 + i) * 64 + lane;
            int row = chunk >> 3, c = chunk & 7;
            GLOAD_LDS16(Wt + (size_t)(n0 + row) * 1024 + k0 + c * 8, &Bl[chunk * 8]);
        }
        __syncthreads();

        #pragma unroll
        for (int kk = 0; kk < 2; kk++) {
            bf16x8 af[4], bfv[2];
            #pragma unroll
            for (int m = 0; m < 4; m++)
                af[m] = *(const bf16x8*)&Al[(wm * 64 + m * 16 + cc) * 64 + kk * 32 + g * 8];
            #pragma unroll
            for (int n = 0; n < 2; n++)
                bfv[n] = *(const bf16x8*)&Bl[(wn * 32 + n * 16 + cc) * 64 + kk * 32 + g * 8];
            #pragma unroll
            for (int m = 0; m < 4; m++)
                #pragma unroll
                for (int n = 0; n < 2; n++)
                    acc[m][n] = __builtin_amdgcn_mfma_f32_16x16x32_bf16(af[m], bfv[n], acc[m][n], 0, 0, 0);
        }
        __syncthreads();
    }

    #pragma unroll
    for (int n = 0; n < 2; n++) {
        int col = n0 + wn * 32 + n * 16 + cc;
        float bv = bias[col];
        #pragma unroll
        for (int m = 0; m < 4; m++) {
            #pragma unroll
            for (int r = 0; r < 4; r++) {
                int row = m0 + wm * 64 + m * 16 + g * 4 + r;
                Out[(size_t)row * 1024 + col] = acc[m][n][r] + bv;
            }
        }
    }
}

// ---------------------------------------------------------------------------
extern "C" void kernel_launch(void* const* d_in, const int* in_sizes, int n_in,
                              void* d_out, int out_size, void* d_ws, size_t ws_size,
                              hipStream_t stream)
{
    const float* x      = (const float*)d_in[0];
    const float* W_attn = (const float*)d_in[1];
    const float* b_attn = (const float*)d_in[2];
    const float* W_proj = (const float*)d_in[3];
    const float* b_proj = (const float*)d_in[4];
    float* out = (float*)d_out;

    const size_t SZ = (size_t)4096 * 1024;
    short* R1 = (short*)d_ws;                  // Wt_attn, later Aout
    short* Qw = R1 + SZ;                       // later Wt_proj
    short* Kw = Qw + SZ;
    short* Vt = Kw + SZ;

    short* Wt_attn = R1;
    short* Aout    = R1;
    short* Wt_proj = Qw;
    short* Xb      = (short*)d_out;            // d_out as bf16 scratch until proj

    convx<<<dim3(2048), 256, 0, stream>>>(x, Xb);
    convt<<<dim3(48, 16), 256, 0, stream>>>(W_attn, Wt_attn, 1024, 3072);
    qkv_gemm<<<dim3(256), 512, 0, stream>>>(Xb, Wt_attn, b_attn, Qw, Kw, Vt);
    attn_v7c<<<dim3(2048), 256, 0, stream>>>(Qw, Kw, Vt, Aout);
    convt<<<dim3(16, 16), 256, 0, stream>>>(W_proj, Wt_proj, 1024, 1024);
    proj_gemm<<<dim3(16, 32), 256, 0, stream>>>(Aout, Wt_proj, b_proj, out);
}

// Round 11
// 148.336 us; speedup vs baseline: 1.3868x; 1.0205x over previous
//
#include <hip/hip_runtime.h>
#include <hip/hip_bf16.h>

// B=2, T=2048, C=1024, H=16, D=64
// convx(X) -> convt(W_attn) -> qkv_gemm (256x192 8-wave counted-vmcnt) ->
// attn_v8 (4 waves share KV stream via L1; no merge) -> convt(W_proj) -> proj_gemm

typedef __attribute__((ext_vector_type(8))) short bf16x8;
typedef __attribute__((ext_vector_type(4))) short bf16x4;
typedef __attribute__((ext_vector_type(4))) float f32x4;

__device__ __forceinline__ short f2bs(float f) {
    union { __hip_bfloat16 h; short s; } u;
    u.h = __float2bfloat16(f);
    return u.s;
}

__device__ __forceinline__ short f2bs_trunc(float f) {
    return (short)(__float_as_uint(f) >> 16);
}

#define GLOAD_LDS16(gp, lp)                                                        \
    __builtin_amdgcn_global_load_lds((const __attribute__((address_space(1))) void*)(gp), \
                                     (__attribute__((address_space(3))) void*)(lp), 16, 0, 0)

// ---------------------------------------------------------------------------
// convx: X f32 [4096*1024] -> bf16.
// ---------------------------------------------------------------------------
__global__ __launch_bounds__(256) void convx(
    const float* __restrict__ X, short* __restrict__ Xb)
{
    const size_t i = ((size_t)blockIdx.x * 256 + threadIdx.x) * 8;
    float4 a = *(const float4*)(X + i);
    float4 b = *(const float4*)(X + i + 4);
    bf16x8 s;
    s[0] = f2bs(a.x); s[1] = f2bs(a.y); s[2] = f2bs(a.z); s[3] = f2bs(a.w);
    s[4] = f2bs(b.x); s[5] = f2bs(b.y); s[6] = f2bs(b.z); s[7] = f2bs(b.w);
    *(bf16x8*)(Xb + i) = s;
}

// ---------------------------------------------------------------------------
// convert + transpose: W f32 [K][N] -> Wt bf16 [N][K].
// ---------------------------------------------------------------------------
__global__ __launch_bounds__(256) void convt(
    const float* __restrict__ W, short* __restrict__ Wt, int K, int N)
{
    __shared__ short t[64 * 72];
    const int tid = threadIdx.x;
    const int n0 = blockIdx.x * 64, k0 = blockIdx.y * 64;
    #pragma unroll
    for (int i = 0; i < 4; i++) {
        int k = (tid >> 4) + i * 16;
        int n = (tid & 15) * 4;
        float4 v = *(const float4*)(W + (size_t)(k0 + k) * N + n0 + n);
        t[(n + 0) * 72 + k] = f2bs(v.x);
        t[(n + 1) * 72 + k] = f2bs(v.y);
        t[(n + 2) * 72 + k] = f2bs(v.z);
        t[(n + 3) * 72 + k] = f2bs(v.w);
    }
    __syncthreads();
    #pragma unroll
    for (int i = 0; i < 2; i++) {
        int n  = (tid >> 3) + i * 32;
        int kc = (tid & 7) * 8;
        bf16x8 v = *(const bf16x8*)&t[n * 72 + kc];
        *(bf16x8*)(Wt + (size_t)(n0 + n) * K + k0 + kc) = v;
    }
}

// ---------------------------------------------------------------------------
// Kernel 1: QKV GEMM, 256x192 tile, BK=64, 8 waves, double-buffered LDS with
// counted vmcnt, swizzled reads, setprio.
// ---------------------------------------------------------------------------
__global__ __launch_bounds__(512) void qkv_gemm(
    const short* __restrict__ Xb, const short* __restrict__ Wt,
    const float* __restrict__ bias,
    short* __restrict__ Qw, short* __restrict__ Kw, short* __restrict__ Vt)
{
    __shared__ short Alds[2][256 * 64];
    __shared__ short Blds[2][192 * 64];
    const int tid  = threadIdx.x;
    const int lane = tid & 63;
    const int wid  = tid >> 6;
    const int wm = wid >> 2, wn = wid & 3;
    const int g = lane >> 4, cc = lane & 15;
    const int sw = cc & 7;

    const int bid  = blockIdx.x;
    const int wgid = (bid & 7) * 32 + (bid >> 3);
    const int n0 = (wgid >> 4) * 192;
    const int m0 = (wgid & 15) * 256;

    f32x4 acc[8][3];
    const f32x4 z4 = {0.f, 0.f, 0.f, 0.f};
    #pragma unroll
    for (int i = 0; i < 8; i++)
        #pragma unroll
        for (int j = 0; j < 3; j++) acc[i][j] = z4;

    auto STAGE = [&](int t, int buf) {
        const int k0 = t * 64;
        #pragma unroll
        for (int j = 0; j < 4; j++) {
            int c = j * 512 + wid * 64 + lane;
            int row = c >> 3, sch = (c & 7) ^ (row & 7);
            GLOAD_LDS16(Xb + (size_t)(m0 + row) * 1024 + k0 + sch * 8,
                        &Alds[buf][c * 8]);
        }
        #pragma unroll
        for (int j = 0; j < 3; j++) {
            int c = j * 512 + wid * 64 + lane;
            int row = c >> 3, sch = (c & 7) ^ (row & 7);
            GLOAD_LDS16(Wt + (size_t)(n0 + row) * 1024 + k0 + sch * 8,
                        &Blds[buf][c * 8]);
        }
    };

    STAGE(0, 0);
    STAGE(1, 1);
    asm volatile("s_waitcnt vmcnt(7)" ::: "memory");
    asm volatile("s_barrier" ::: "memory");

    const int NT = 16;
    for (int t = 0; t < NT; t++) {
        const short* Ab = Alds[t & 1];
        const short* Bb = Blds[t & 1];

        bf16x8 bfr[3][2];
        #pragma unroll
        for (int nf = 0; nf < 3; nf++)
            #pragma unroll
            for (int kk = 0; kk < 2; kk++)
                bfr[nf][kk] = *(const bf16x8*)&Bb[(wn * 48 + nf * 16 + cc) * 64 +
                                                  ((kk * 4 + g) ^ sw) * 8];
        {
            bf16x8 af[4][2];
            #pragma unroll
            for (int mf = 0; mf < 4; mf++)
                #pragma unroll
                for (int kk = 0; kk < 2; kk++)
                    af[mf][kk] = *(const bf16x8*)&Ab[(wm * 128 + mf * 16 + cc) * 64 +
                                                     ((kk * 4 + g) ^ sw) * 8];
            __builtin_amdgcn_s_setprio(1);
            #pragma unroll
            for (int mf = 0; mf < 4; mf++)
                #pragma unroll
                for (int nf = 0; nf < 3; nf++)
                    #pragma unroll
                    for (int kk = 0; kk < 2; kk++)
                        acc[mf][nf] = __builtin_amdgcn_mfma_f32_16x16x32_bf16(
                            af[mf][kk], bfr[nf][kk], acc[mf][nf], 0, 0, 0);
            __builtin_amdgcn_s_setprio(0);
        }
        {
            bf16x8 af[4][2];
            #pragma unroll
            for (int mf = 0; mf < 4; mf++)
                #pragma unroll
                for (int kk = 0; kk < 2; kk++)
                    af[mf][kk] = *(const bf16x8*)&Ab[(wm * 128 + (mf + 4) * 16 + cc) * 64 +
                                                     ((kk * 4 + g) ^ sw) * 8];
            __builtin_amdgcn_s_setprio(1);
            #pragma unroll
            for (int mf = 0; mf < 4; mf++)
                #pragma unroll
                for (int nf = 0; nf < 3; nf++)
                    #pragma unroll
                    for (int kk = 0; kk < 2; kk++)
                        acc[mf + 4][nf] = __builtin_amdgcn_mfma_f32_16x16x32_bf16(
                            af[mf][kk], bfr[nf][kk], acc[mf + 4][nf], 0, 0, 0);
            __builtin_amdgcn_s_setprio(0);
        }

        asm volatile("s_barrier" ::: "memory");
        if (t + 2 < NT) {
            STAGE(t + 2, t & 1);
            asm volatile("s_waitcnt vmcnt(7)" ::: "memory");
            asm volatile("s_barrier" ::: "memory");
        } else if (t + 1 < NT) {
            asm volatile("s_waitcnt vmcnt(0)" ::: "memory");
            asm volatile("s_barrier" ::: "memory");
        }
    }

    const float QSCALE = 0.04508422976f;
    #pragma unroll
    for (int nf = 0; nf < 3; nf++) {
        int col = n0 + wn * 48 + nf * 16 + cc;
        int which = col >> 10;
        int ci = col & 1023;
        int h = ci >> 6, d = ci & 63;
        float bv = bias[col];
        #pragma unroll
        for (int mf = 0; mf < 8; mf++) {
            #pragma unroll
            for (int r = 0; r < 4; r++) {
                int row = m0 + wm * 128 + mf * 16 + g * 4 + r;
                int b = row >> 11, tt = row & 2047;
                int bh = b * 16 + h;
                float v = acc[mf][nf][r] + bv;
                if (which == 0)      Qw[((size_t)bh * 2048 + tt) * 64 + d] = f2bs(v * QSCALE);
                else if (which == 1) Kw[((size_t)bh * 2048 + tt) * 64 + d] = f2bs(v);
                else {
                    int tp = (tt & ~31) | (((tt >> 2) & 3) * 8 + ((tt >> 4) & 1) * 4 + (tt & 3));
                    Vt[((size_t)bh * 64 + d) * 2048 + tp] = f2bs(v);
                }
            }
        }
    }
}

// ---------------------------------------------------------------------------
// Kernel 2: causal flash attention v8. 256-thr block = 4 waves on 4
// CONSECUTIVE 32-row q-tiles of the SAME head -> the 4 waves issue identical
// K/V addresses in near-lockstep and share via L1 (4x fewer L2 requests).
// No barriers, no merge. Step body identical to v6 (proven). P-conversion
// uses truncation (P in [0,1], bias <=0.2%).
// Grid: 512 blocks (2/CU); pairing (15-k, k) makes per-CU work constant (68).
// ---------------------------------------------------------------------------
#define ATTN_STEP(KF, VF, KN, VN, KVN, PRE, MSK, KV0)                             \
  {                                                                               \
    if (PRE) {                                                                    \
      _Pragma("unroll") for (int kvc = 0; kvc < 2; kvc++)                         \
      _Pragma("unroll") for (int ds = 0; ds < 2; ds++)                            \
        KN[kvc * 2 + ds] = *(const bf16x8*)(Kb + ((KVN) + kvc * 16 + cc) * 64 + ds * 32 + g * 8); \
      _Pragma("unroll") for (int ch = 0; ch < 4; ch++)                            \
        VN[ch] = *(const bf16x8*)(Vb + (ch * 16 + cc) * 2048 + (KVN) + g * 8);     \
    }                                                                             \
    f32x4 s_[2][2];                                                               \
    _Pragma("unroll") for (int qf = 0; qf < 2; qf++)                              \
    _Pragma("unroll") for (int kvc = 0; kvc < 2; kvc++) {                         \
      s_[qf][kvc] = z4;                                                           \
      _Pragma("unroll") for (int ds = 0; ds < 2; ds++)                            \
        s_[qf][kvc] = __builtin_amdgcn_mfma_f32_16x16x32_bf16(                    \
            KF[kvc * 2 + ds], qfr[qf][ds], s_[qf][kvc], 0, 0, 0);                 \
    }                                                                             \
    bf16x8 pb_[2];                                                                \
    _Pragma("unroll") for (int qf = 0; qf < 2; qf++) {                            \
      float sv[8];                                                                \
      _Pragma("unroll") for (int kvc = 0; kvc < 2; kvc++)                         \
      _Pragma("unroll") for (int r = 0; r < 4; r++) {                             \
        float v = s_[qf][kvc][r];                                                 \
        if (MSK) {                                                                \
          int kv = (KV0) + kvc * 16 + g * 4 + r;                                  \
          v = (kv <= q0 + qf * 16 + cc) ? v : -1e30f;                             \
        }                                                                         \
        sv[kvc * 4 + r] = v;                                                      \
      }                                                                           \
      float lm = fmaxf(fmaxf(fmaxf(sv[0], sv[1]), fmaxf(sv[2], sv[3])),           \
                       fmaxf(fmaxf(sv[4], sv[5]), fmaxf(sv[6], sv[7])));          \
      if (__any(lm > m_r[qf] + 6.0f)) {                                           \
        float mx = lm;                                                            \
        mx = fmaxf(mx, __shfl_xor(mx, 16));                                       \
        mx = fmaxf(mx, __shfl_xor(mx, 32));                                       \
        float mn = fmaxf(m_r[qf], mx);                                            \
        float a = exp2f(m_r[qf] - mn);                                            \
        _Pragma("unroll") for (int ch = 0; ch < 4; ch++)                          \
        _Pragma("unroll") for (int r = 0; r < 4; r++) o[qf][ch][r] *= a;          \
        l_l[qf] *= a;                                                             \
        m_r[qf] = mn;                                                             \
      }                                                                           \
      float rs = 0.f;                                                             \
      _Pragma("unroll") for (int i = 0; i < 8; i++) {                             \
        float p = exp2f(sv[i] - m_r[qf]);                                         \
        pb_[qf][i] = f2bs_trunc(p);                                               \
        rs += p;                                                                  \
      }                                                                           \
      l_l[qf] += rs;                                                              \
    }                                                                             \
    _Pragma("unroll") for (int ch = 0; ch < 4; ch++) {                            \
      o[0][ch] = __builtin_amdgcn_mfma_f32_16x16x32_bf16(VF[ch], pb_[0], o[0][ch], 0, 0, 0); \
      o[1][ch] = __builtin_amdgcn_mfma_f32_16x16x32_bf16(VF[ch], pb_[1], o[1][ch], 0, 0, 0); \
    }                                                                             \
  }

__global__ __launch_bounds__(256) void attn_v8(
    const short* __restrict__ Qw, const short* __restrict__ Kw,
    const short* __restrict__ Vt, short* __restrict__ Aout)
{
    const int tid  = threadIdx.x;
    const int lane = tid & 63;
    const int ws   = tid >> 6;            // q-tile index within block 0..3
    const int g = lane >> 4, cc = lane & 15;
    const int bid = blockIdx.x;
    const int bh = bid & 31;              // XCD = bh % 8 -> per-head L2 locality
    const int k  = bid >> 5;              // 0..15
    const int g4 = (k < 8) ? (15 - k) : (k - 8);   // complementary pairing
    const int qt = g4 * 4 + ws;           // this wave's 32-row q-tile
    const int q0 = qt * 32;
    const int b = bh >> 4, h = bh & 15;
    const short* Qb = Qw + (size_t)bh * 2048 * 64;
    const short* Kb = Kw + (size_t)bh * 2048 * 64;
    const short* Vb = Vt + (size_t)bh * 64 * 2048;

    bf16x8 qfr[2][2];
    #pragma unroll
    for (int qf = 0; qf < 2; qf++)
        #pragma unroll
        for (int ds = 0; ds < 2; ds++)
            qfr[qf][ds] = *(const bf16x8*)(Qb + (q0 + qf * 16 + cc) * 64 + ds * 32 + g * 8);

    const f32x4 z4 = {0.f, 0.f, 0.f, 0.f};
    f32x4 o[2][4];
    #pragma unroll
    for (int qf = 0; qf < 2; qf++)
        #pragma unroll
        for (int ch = 0; ch < 4; ch++) o[qf][ch] = z4;
    float m_r[2] = {-1e30f, -1e30f};
    float l_l[2] = {0.f, 0.f};

    bf16x8 kA[4], vA[4], kB[4], vB[4];
    #pragma unroll
    for (int kvc = 0; kvc < 2; kvc++)
        #pragma unroll
        for (int ds = 0; ds < 2; ds++)
            kA[kvc * 2 + ds] = *(const bf16x8*)(Kb + (kvc * 16 + cc) * 64 + ds * 32 + g * 8);
    #pragma unroll
    for (int ch = 0; ch < 4; ch++)
        vA[ch] = *(const bf16x8*)(Vb + (ch * 16 + cc) * 2048 + g * 8);

    int st = 0;
    while (st + 2 <= qt) {
        ATTN_STEP(kA, vA, kB, vB, (st + 1) * 32, 1, 0, 0);
        ATTN_STEP(kB, vB, kA, vA, (st + 2) * 32, 1, 0, 0);
        st += 2;
    }
    if (st < qt) {
        ATTN_STEP(kA, vA, kB, vB, (st + 1) * 32, 1, 0, 0);
        ATTN_STEP(kB, vB, kB, vB, 0, 0, 1, qt * 32);
    } else {
        ATTN_STEP(kA, vA, kA, vA, 0, 0, 1, qt * 32);
    }

    // epilogue: reduce l across g-lanes, write O^T cols q=cc
    #pragma unroll
    for (int qf = 0; qf < 2; qf++) {
        float lt = l_l[qf];
        lt += __shfl_xor(lt, 16);
        lt += __shfl_xor(lt, 32);
        float rl = 1.0f / lt;
        const int t = q0 + qf * 16 + cc;
        #pragma unroll
        for (int ch = 0; ch < 4; ch++) {
            bf16x4 ov;
            #pragma unroll
            for (int r = 0; r < 4; r++) ov[r] = f2bs(o[qf][ch][r] * rl);
            *(bf16x4*)(Aout + ((size_t)b * 2048 + t) * 1024 + h * 64 + ch * 16 + g * 4) = ov;
        }
    }
}

// ---------------------------------------------------------------------------
// Kernel 3: projection. 128x64 tile (512 blocks = 2/CU).
// ---------------------------------------------------------------------------
__global__ __launch_bounds__(256) void proj_gemm(
    const short* __restrict__ A, const short* __restrict__ Wt,
    const float* __restrict__ bias, float* __restrict__ Out)
{
    __shared__ short Al[128 * 64];
    __shared__ short Bl[64 * 64];
    const int tid  = threadIdx.x;
    const int lane = tid & 63;
    const int wid  = tid >> 6;
    const int wm = wid >> 1, wn = wid & 1;
    const int g = lane >> 4, cc = lane & 15;
    const int m0 = blockIdx.y * 128, n0 = blockIdx.x * 64;

    f32x4 acc[4][2];
    const f32x4 z4 = {0.f, 0.f, 0.f, 0.f};
    #pragma unroll
    for (int i = 0; i < 4; i++)
        #pragma unroll
        for (int j = 0; j < 2; j++) acc[i][j] = z4;

    for (int k0 = 0; k0 < 1024; k0 += 64) {
        #pragma unroll
        for (int i = 0; i < 4; i++) {
            int chunk = (wid * 4 + i) * 64 + lane;
            int row = chunk >> 3, c = chunk & 7;
            GLOAD_LDS16(A + (size_t)(m0 + row) * 1024 + k0 + c * 8, &Al[chunk * 8]);
        }
        #pragma unroll
        for (int i = 0; i < 2; i++) {
            int chunk = (wid * 2 + i) * 64 + lane;
            int row = chunk >> 3, c = chunk & 7;
            GLOAD_LDS16(Wt + (size_t)(n0 + row) * 1024 + k0 + c * 8, &Bl[chunk * 8]);
        }
        __syncthreads();

        #pragma unroll
        for (int kk = 0; kk < 2; kk++) {
            bf16x8 af[4], bfv[2];
            #pragma unroll
            for (int m = 0; m < 4; m++)
                af[m] = *(const bf16x8*)&Al[(wm * 64 + m * 16 + cc) * 64 + kk * 32 + g * 8];
            #pragma unroll
            for (int n = 0; n < 2; n++)
                bfv[n] = *(const bf16x8*)&Bl[(wn * 32 + n * 16 + cc) * 64 + kk * 32 + g * 8];
            #pragma unroll
            for (int m = 0; m < 4; m++)
                #pragma unroll
                for (int n = 0; n < 2; n++)
                    acc[m][n] = __builtin_amdgcn_mfma_f32_16x16x32_bf16(af[m], bfv[n], acc[m][n], 0, 0, 0);
        }
        __syncthreads();
    }

    #pragma unroll
    for (int n = 0; n < 2; n++) {
        int col = n0 + wn * 32 + n * 16 + cc;
        float bv = bias[col];
        #pragma unroll
        for (int m = 0; m < 4; m++) {
            #pragma unroll
            for (int r = 0; r < 4; r++) {
                int row = m0 + wm * 64 + m * 16 + g * 4 + r;
                Out[(size_t)row * 1024 + col] = acc[m][n][r] + bv;
            }
        }
    }
}

// ---------------------------------------------------------------------------
extern "C" void kernel_launch(void* const* d_in, const int* in_sizes, int n_in,
                              void* d_out, int out_size, void* d_ws, size_t ws_size,
                              hipStream_t stream)
{
    const float* x      = (const float*)d_in[0];
    const float* W_attn = (const float*)d_in[1];
    const float* b_attn = (const float*)d_in[2];
    const float* W_proj = (const float*)d_in[3];
    const float* b_proj = (const float*)d_in[4];
    float* out = (float*)d_out;

    const size_t SZ = (size_t)4096 * 1024;
    short* R1 = (short*)d_ws;                  // Wt_attn, later Aout
    short* Qw = R1 + SZ;                       // later Wt_proj
    short* Kw = Qw + SZ;
    short* Vt = Kw + SZ;

    short* Wt_attn = R1;
    short* Aout    = R1;
    short* Wt_proj = Qw;
    short* Xb      = (short*)d_out;            // d_out as bf16 scratch until proj

    convx<<<dim3(2048), 256, 0, stream>>>(x, Xb);
    convt<<<dim3(48, 16), 256, 0, stream>>>(W_attn, Wt_attn, 1024, 3072);
    qkv_gemm<<<dim3(256), 512, 0, stream>>>(Xb, Wt_attn, b_attn, Qw, Kw, Vt);
    attn_v8<<<dim3(512), 256, 0, stream>>>(Qw, Kw, Vt, Aout);
    convt<<<dim3(16, 16), 256, 0, stream>>>(W_proj, Wt_proj, 1024, 1024);
    proj_gemm<<<dim3(16, 32), 256, 0, stream>>>(Aout, Wt_proj, b_proj, out);
}